// Round 12
// baseline (180.449 us; speedup 1.0000x reference)
//
#include <hip/hip_runtime.h>
#include <stdint.h>

#define BB 4
#define SS 2048
#define EE 1024
#define HH 16
#define DD 64
#define MM (BB*SS)   // 8192

typedef unsigned short u16;
typedef __attribute__((ext_vector_type(8))) short bf16x8;
typedef __attribute__((ext_vector_type(4))) float f32x4;

#define MFMA __builtin_amdgcn_mfma_f32_16x16x32_bf16

#if __has_builtin(__builtin_amdgcn_exp2f)
#define EXP2(x) __builtin_amdgcn_exp2f(x)
#else
#define EXP2(x) exp2f(x)
#endif

__device__ __forceinline__ u16 f2bf(float f) {
  union { float f; uint32_t u; } x; x.f = f;
  uint32_t r = (x.u + 0x7fffu + ((x.u >> 16) & 1u)) >> 16;
  return (u16)r;
}

__device__ __forceinline__ uint32_t cvtpk(float lo, float hi) {
  uint32_t r;
  asm volatile("v_cvt_pk_bf16_f32 %0, %1, %2" : "=v"(r) : "v"(lo), "v"(hi));
  return r;
}

__device__ __forceinline__ void gl_lds16(const void* g, void* l) {
  __builtin_amdgcn_global_load_lds(
      (const __attribute__((address_space(1))) uint32_t*)g,
      (__attribute__((address_space(3))) uint32_t*)l, 16, 0, 0);
}

// ---------------- weight-only cast fp32 -> bf16 (12 MB total) ----------------
__global__ __launch_bounds__(256) void cast_w(
    const float* __restrict__ s0, const float* __restrict__ s1,
    const float* __restrict__ s2, const float* __restrict__ s3,
    u16* __restrict__ d0, u16* __restrict__ d1,
    u16* __restrict__ d2, u16* __restrict__ d3) {
  int i = blockIdx.x * 256 + threadIdx.x;          // [0, 4*2^17)
  int sel = i >> 17, off = i & ((1 << 17) - 1);
  const float* s = sel == 0 ? s0 : sel == 1 ? s1 : sel == 2 ? s2 : s3;
  u16* d = sel == 0 ? d0 : sel == 1 ? d1 : sel == 2 ? d2 : d3;
  const float4* sp = (const float4*)s;
  float4 a = sp[off*2], b = sp[off*2+1];
  union { u16 h[8]; uint4 v; } o;
  o.h[0]=f2bf(a.x); o.h[1]=f2bf(a.y); o.h[2]=f2bf(a.z); o.h[3]=f2bf(a.w);
  o.h[4]=f2bf(b.x); o.h[5]=f2bf(b.y); o.h[6]=f2bf(b.z); o.h[7]=f2bf(b.w);
  *(uint4*)(d + (size_t)off*8) = o.v;
}

// ---------------- GEMM core v2: 2-phase dbuf + bank-swizzled tiles ----------
// Loop shape = attn9's verified pattern: stage(t+1, other buf) -> compute(t)
// -> ONE barrier. bf16 tiles (B always; A when !A_FP32) use slot-XOR
// (st ^ ((row>>1)&3)) on BOTH source and read -> 2-way banks (was 8-way,
// 9.4e6 conflicts/dispatch measured R11). fp32 A tile: slot ^ (row&7),
// 2-way verified. A_FP32 converts via v_cvt_pk on the fragment read.
template<int A_FP32, int OUT_BF16>
__device__ __forceinline__ void gemm_body(
    const void* __restrict__ Ap, const u16* __restrict__ W,
    const float* __restrict__ bias, void* __restrict__ Cout,
    int Ndim, int Kdim, float scale, int m0, int n0,
    char* AsB, char* BsB) {
  const int tid = threadIdx.x;
  const int lane = tid & 63, w = tid >> 6;
  const int wr = w >> 1, wc = w & 1;
  const int l15 = lane & 15, l4 = lane >> 4;

  f32x4 acc[4][4] = {};

  // B staging (bf16): swizzled source slot
  const int srow = tid >> 2, st = tid & 3;
  const int ssw = st ^ ((srow >> 1) & 3);
  const u16* bg = W + (size_t)(n0 + srow) * Kdim + ssw * 8;
  const size_t rstrideB = (size_t)64 * Kdim;

  // A staging
  const int ar = tid >> 3, asl = tid & 7;
  const int asw = asl ^ (ar & 7);
  const float* agf = nullptr;
  const u16*   agh = nullptr;
  if (A_FP32) agf = (const float*)Ap + (size_t)(m0 + ar) * Kdim + asw * 4;
  else        agh = (const u16*)Ap + (size_t)(m0 + srow) * Kdim + ssw * 8;

  auto stage = [&](int k0, int bi) {
    if (A_FP32) {
      #pragma unroll
      for (int i = 0; i < 4; ++i)   // rows i*32+ar; (row&7)==(ar&7) since 32|i*32
        gl_lds16(agf + (size_t)i*32*Kdim + k0, AsB + bi*16384 + i*4096 + tid*16);
    } else {
      gl_lds16(agh + k0,                    AsB + bi*8192 + tid*16);
      gl_lds16(agh + k0 + (size_t)64*Kdim,  AsB + bi*8192 + 4096 + tid*16);
    }
    gl_lds16(bg + k0,            BsB + bi*8192 + tid*16);
    gl_lds16(bg + k0 + rstrideB, BsB + bi*8192 + 4096 + tid*16);
  };

  stage(0, 0);
  __syncthreads();

  const int T = Kdim / 32;
  for (int t = 0; t < T; ++t) {
    const int bi = t & 1;
    if (t + 1 < T) stage((t + 1) * 32, bi ^ 1);

    bf16x8 af[4], bfr[4];
    #pragma unroll
    for (int m = 0; m < 4; ++m) {
      int r = wr*64 + m*16 + l15;
      if (A_FP32) {
        const char* rb = AsB + bi*16384 + r*128;
        f32x4 fa = *(const f32x4*)(rb + (((l4*2    ) ^ (r & 7)) * 16));
        f32x4 fb = *(const f32x4*)(rb + (((l4*2 + 1) ^ (r & 7)) * 16));
        union { uint32_t u[4]; bf16x8 v; } cv;
        cv.u[0] = cvtpk(fa[0], fa[1]);
        cv.u[1] = cvtpk(fa[2], fa[3]);
        cv.u[2] = cvtpk(fb[0], fb[1]);
        cv.u[3] = cvtpk(fb[2], fb[3]);
        af[m] = cv.v;
      } else {
        af[m] = *(const bf16x8*)(AsB + bi*8192 + r*64 + ((l4 ^ ((r >> 1) & 3)) * 16));
      }
    }
    #pragma unroll
    for (int n = 0; n < 4; ++n) {
      int rr = wc*64 + n*16 + l15;
      bfr[n] = *(const bf16x8*)(BsB + bi*8192 + rr*64 + ((l4 ^ ((rr >> 1) & 3)) * 16));
    }
    #pragma unroll
    for (int m = 0; m < 4; ++m)
      #pragma unroll
      for (int n = 0; n < 4; ++n)
        acc[m][n] = MFMA(af[m], bfr[n], acc[m][n], 0, 0, 0);
    __syncthreads();   // stage(t+1) visible; reads of buf bi done
  }

  const int ccol = wc*64 + l15;
  float bv[4];
  #pragma unroll
  for (int n = 0; n < 4; ++n) bv[n] = bias[n0 + ccol + n*16];
  #pragma unroll
  for (int m = 0; m < 4; ++m) {
    #pragma unroll
    for (int i = 0; i < 4; ++i) {
      size_t row = (size_t)(m0 + wr*64 + m*16 + l4*4 + i);
      #pragma unroll
      for (int n = 0; n < 4; ++n) {
        float v = (acc[m][n][i] + bv[n]) * scale;
        size_t idx = row * Ndim + (n0 + ccol + n*16);
        if (OUT_BF16) ((u16*)Cout)[idx] = f2bf(v);
        else          ((float*)Cout)[idx] = v;
      }
    }
  }
}

// merged Q/K/V projections, fp32-A staging, XCD chunk-swizzle (R11-verified).
__global__ __launch_bounds__(256, 2) void gemm_qkv(
    const float* __restrict__ qx, const float* __restrict__ kx, const float* __restrict__ vx,
    const u16* __restrict__ wqm, const u16* __restrict__ wkm, const u16* __restrict__ wvm,
    const float* __restrict__ qbv, const float* __restrict__ kbv, const float* __restrict__ vbv,
    u16* __restrict__ qo, u16* __restrict__ ko, u16* __restrict__ vo) {
  __shared__ alignas(16) char AsB[2*16384];   // 32 KB (fp32 A dbuf)
  __shared__ alignas(16) char BsB[2*8192];    // 16 KB (bf16 B dbuf)
  const int flat = blockIdx.x + blockIdx.y * 8 + blockIdx.z * 512;  // 0..1535
  const int j = flat & 7, s = flat >> 3;        // XCD, slot 0..191
  const int c = 6*j + (s >> 5), i = s & 31;     // chunk 0..47, block in chunk
  const int nx = i & 7;
  const int my = ((c & 15) << 2) + (i >> 3);    // 0..63
  const int z = c >> 4;
  const float* A = z == 0 ? qx : z == 1 ? kx : vx;
  const u16* W = z == 0 ? wqm : z == 1 ? wkm : wvm;
  const float* bias = z == 0 ? qbv : z == 1 ? kbv : vbv;
  u16* C = z == 0 ? qo : z == 1 ? ko : vo;
  const float scale = z == 0 ? 0.125f : 1.0f;
  gemm_body<1,1>(A, W, bias, C, EE, EE, scale, my * 128, nx * 128, AsB, BsB);
}

__global__ __launch_bounds__(256, 4) void gemm_out(
    const u16* __restrict__ A, const u16* __restrict__ W,
    const float* __restrict__ bias, float* __restrict__ Cout) {
  __shared__ alignas(16) char AsB[2*8192];    // 16 KB
  __shared__ alignas(16) char BsB[2*8192];    // 16 KB
  const int flat = blockIdx.x + blockIdx.y * 8;   // 0..511
  const int j = flat & 7, s = flat >> 3;          // XCD, slot 0..63
  const int nx = s & 7, yy = (j << 3) + (s >> 3); // XCD j -> m-panels 8j..8j+7
  gemm_body<0,0>(A, W, bias, Cout, EE, EE, 1.0f, yy * 128, nx * 128, AsB, BsB);
}

// ---------------- causal flash attention v9 (R10-verified, 75.8 us) --------
__global__ __launch_bounds__(256, 2) void attn9(
    const u16* __restrict__ Q, const u16* __restrict__ K,
    const u16* __restrict__ V, u16* __restrict__ ctx) {
  __shared__ alignas(16) u16 Ks[2][2][64*64];    // 32768 B
  __shared__ alignas(16) u16 VTs[2][2][64*64];   // 32768 B
  __shared__ alignas(16) u16 Ps[4][32*64];       // 16384 B

  const int tid = threadIdx.x, lane = tid & 63, w = tid >> 6;
  const int l15 = lane & 15, l4 = lane >> 4;

  const int f = blockIdx.x;               // 0..511
  const int j = f & 7, s = f >> 3;        // XCD, slot
  const int qlo = s & 7;
  const int panel = j * 8 + (s >> 3);     // 0..63
  const int h = panel & 15, b = panel >> 4;
  const size_t base = ((size_t)b * SS) * EE + h * DD;

  const int kr  = tid >> 3;
  const int ksl = tid & 7;
  const int rv  = tid >> 2;
  const int vc  = tid & 3;

  u16* KsE  = (u16*)Ks;
  u16* VTsE = (u16*)VTs;
  u16* PsE  = (u16*)Ps + w * 2048;

  auto stageK = [&](int t, int pb, int sub) {
    #pragma unroll
    for (int i = 0; i < 2; ++i) {
      int row = i*32 + kr;
      gl_lds16(K + base + (size_t)(t*64 + row)*EE + (ksl ^ (row & 7))*8,
               KsE + pb*8192 + sub*4096 + i*2048 + tid*8);
    }
  };
  auto vtWrite = [&](int pb, int sub, bf16x8 v0, bf16x8 v1) {
    #pragma unroll
    for (int jj = 0; jj < 16; ++jj) {
      u16 val = jj < 8 ? (u16)v0[jj] : (u16)v1[jj - 8];
      int d = vc*16 + jj;
      int sl = (rv >> 3) ^ (jj & 7) ^ (vc << 1);
      VTsE[pb*8192 + sub*4096 + d*64 + sl*8 + (rv & 7)] = val;
    }
  };

  #pragma unroll 1
  for (int pass = 0; pass < 2; ++pass) {
    const int qblk = pass == 0 ? (15 - qlo) : qlo;
    const int q0 = qblk * 128, wq = q0 + w * 32;
    const int npairs = qblk + 1;

    bf16x8 qf[2][2];
    #pragma unroll
    for (int G = 0; G < 2; ++G)
      #pragma unroll
      for (int kc = 0; kc < 2; ++kc)
        qf[G][kc] = *(const bf16x8*)(Q + base + (size_t)(wq + G*16 + l15)*EE + kc*32 + l4*8);

    f32x4 o[2][4] = {};
    float lsum[2] = {0.f, 0.f};

    auto computeTile = [&](int t, int pb, int sub) {
      if (wq + 31 < t*64) return;
      const bool g0act = (wq + 15 >= t*64);
      const u16* tileK = KsE + pb*8192 + sub*4096;
      const u16* tileV = VTsE + pb*8192 + sub*4096;

      f32x4 sc[2][4] = {};
      #pragma unroll
      for (int nt = 0; nt < 4; ++nt) {
        int row = nt*16 + l15;
        int sw = row & 7;
        const u16* kb = tileK + row*64;
        bf16x8 kf0 = *(const bf16x8*)(kb + ((l4    ) ^ sw)*8);
        bf16x8 kf1 = *(const bf16x8*)(kb + ((4 + l4) ^ sw)*8);
        sc[1][nt] = MFMA(kf0, qf[1][0], sc[1][nt], 0, 0, 0);
        sc[1][nt] = MFMA(kf1, qf[1][1], sc[1][nt], 0, 0, 0);
        if (g0act) {
          sc[0][nt] = MFMA(kf0, qf[0][0], sc[0][nt], 0, 0, 0);
          sc[0][nt] = MFMA(kf1, qf[0][1], sc[0][nt], 0, 0, 0);
        }
      }

      #pragma unroll
      for (int G = 0; G < 2; ++G) {
        if (G == 0 && !g0act) continue;
        const bool nomask = (t*64 + 63 <= wq + G*16);
        const int qg = wq + G*16 + l15;
        #pragma unroll
        for (int nt = 0; nt < 4; ++nt) {
          float p0 = EXP2(__builtin_fmaf(sc[G][nt][0], 1.44269504f, -17.3123405f));
          float p1 = EXP2(__builtin_fmaf(sc[G][nt][1], 1.44269504f, -17.3123405f));
          float p2 = EXP2(__builtin_fmaf(sc[G][nt][2], 1.44269504f, -17.3123405f));
          float p3 = EXP2(__builtin_fmaf(sc[G][nt][3], 1.44269504f, -17.3123405f));
          if (!nomask) {
            int kvs = t*64 + nt*16 + l4*4;
            if (kvs + 0 > qg) p0 = 0.f;
            if (kvs + 1 > qg) p1 = 0.f;
            if (kvs + 2 > qg) p2 = 0.f;
            if (kvs + 3 > qg) p3 = 0.f;
          }
          lsum[G] += (p0 + p1) + (p2 + p3);
          uint2 pk;
          pk.x = cvtpk(p0, p1);
          pk.y = cvtpk(p2, p3);
          *(uint2*)((char*)PsE + (G*16 + l15)*128
                        + (((nt*2 + (l4 >> 1)) ^ (l15 & 7)) * 16)
                        + (l4 & 1) * 8) = pk;
        }
      }

      #pragma unroll
      for (int cc = 0; cc < 2; ++cc) {
        bf16x8 pf1 = *(const bf16x8*)((char*)PsE + (16 + l15)*128
                                     + (((cc*4 + l4) ^ (l15 & 7)) * 16));
        bf16x8 pf0;
        if (g0act)
          pf0 = *(const bf16x8*)((char*)PsE + l15*128
                                     + (((cc*4 + l4) ^ (l15 & 7)) * 16));
        #pragma unroll
        for (int dm = 0; dm < 4; ++dm) {
          int sl = (cc*4 + l4) ^ (l15 & 7) ^ (dm << 1);
          bf16x8 vfv = *(const bf16x8*)(tileV + (dm*16 + l15)*64 + sl*8);
          o[1][dm] = MFMA(pf1, vfv, o[1][dm], 0, 0, 0);
          if (g0act) o[0][dm] = MFMA(pf0, vfv, o[0][dm], 0, 0, 0);
        }
      }
    };

    {
      const u16* va = V + base + (size_t)rv*EE + vc*16;
      const u16* vb = V + base + (size_t)(64 + rv)*EE + vc*16;
      bf16x8 a0 = *(const bf16x8*)va, a1 = *(const bf16x8*)(va + 8);
      bf16x8 b0 = *(const bf16x8*)vb, b1 = *(const bf16x8*)(vb + 8);
      stageK(0, 0, 0);
      stageK(1, 0, 1);
      vtWrite(0, 0, a0, a1);
      vtWrite(0, 1, b0, b1);
    }
    __syncthreads();

    for (int u = 0; u < npairs; ++u) {
      const int cur = u & 1;
      const bool havenext = (u + 1 < npairs);
      bf16x8 na0, na1, nb0, nb1;
      if (havenext) {
        const u16* va = V + base + (size_t)((2*u+2)*64 + rv)*EE + vc*16;
        const u16* vb = V + base + (size_t)((2*u+3)*64 + rv)*EE + vc*16;
        na0 = *(const bf16x8*)va; na1 = *(const bf16x8*)(va + 8);
        nb0 = *(const bf16x8*)vb; nb1 = *(const bf16x8*)(vb + 8);
        stageK(2*u+2, cur ^ 1, 0);
        stageK(2*u+3, cur ^ 1, 1);
      }

      computeTile(2*u, cur, 0);
      if (havenext) vtWrite(cur ^ 1, 0, na0, na1);
      computeTile(2*u + 1, cur, 1);
      if (havenext) vtWrite(cur ^ 1, 1, nb0, nb1);
      __syncthreads();
    }

    #pragma unroll
    for (int G = 0; G < 2; ++G) {
      float r = lsum[G];
      r += __shfl_xor(r, 16);
      r += __shfl_xor(r, 32);
      lsum[G] = 1.0f / r;
    }

    #pragma unroll
    for (int G = 0; G < 2; ++G)
      #pragma unroll
      for (int i = 0; i < 4; ++i) {
        float invv = __shfl(lsum[G], l4*4 + i);
        size_t roff = base + (size_t)(wq + G*16 + l4*4 + i) * EE;
        #pragma unroll
        for (int dm = 0; dm < 4; ++dm)
          ctx[roff + dm*16 + l15] = f2bf(o[G][dm][i] * invv);
      }
  }
}

// ---------------- launch ----------------
extern "C" void kernel_launch(void* const* d_in, const int* in_sizes, int n_in,
                              void* d_out, int out_size, void* d_ws, size_t ws_size,
                              hipStream_t stream) {
  const float* query = (const float*)d_in[0];
  const float* key   = (const float*)d_in[1];
  const float* value = (const float*)d_in[2];
  const float* q_w = (const float*)d_in[4];
  const float* q_b = (const float*)d_in[5];
  const float* k_w = (const float*)d_in[6];
  const float* k_b = (const float*)d_in[7];
  const float* v_w = (const float*)d_in[8];
  const float* v_b = (const float*)d_in[9];
  const float* o_w = (const float*)d_in[10];
  const float* o_b = (const float*)d_in[11];

  char* ws = (char*)d_ws;
  const size_t XB = (size_t)MM * EE * 2;   // 16 MB bf16 activation
  const size_t WB = (size_t)EE * EE * 2;   // 2 MB bf16 weight
  u16* wq = (u16*)(ws);
  u16* wk = (u16*)(ws + WB);
  u16* wv = (u16*)(ws + 2*WB);
  u16* wo = (u16*)(ws + 3*WB);
  u16* qp = (u16*)(ws + 4*WB);
  u16* kp = (u16*)(ws + 4*WB + XB);
  u16* vp = (u16*)(ws + 4*WB + 2*XB);
  u16* ctxb = (u16*)(ws + 4*WB + 3*XB);

  const int nw8 = EE * EE / 8;   // 2^17
  cast_w<<<4*nw8/256, 256, 0, stream>>>(q_w, k_w, v_w, o_w, wq, wk, wv, wo);

  gemm_qkv<<<dim3(8, 64, 3), 256, 0, stream>>>(
      query, key, value, wq, wk, wv, q_b, k_b, v_b, qp, kp, vp);

  attn9<<<512, 256, 0, stream>>>(qp, kp, vp, ctxb);

  gemm_out<<<dim3(EE/128, MM/128), 256, 0, stream>>>(ctxb, wo, o_b, (float*)d_out);
}

// Round 13
// 166.500 us; speedup vs baseline: 1.0838x; 1.0838x over previous
//
#include <hip/hip_runtime.h>
#include <stdint.h>

#define BB 4
#define SS 2048
#define EE 1024
#define HH 16
#define DD 64
#define MM (BB*SS)   // 8192

typedef unsigned short u16;
typedef __attribute__((ext_vector_type(8))) short bf16x8;
typedef __attribute__((ext_vector_type(4))) float f32x4;

#define MFMA __builtin_amdgcn_mfma_f32_16x16x32_bf16

#if __has_builtin(__builtin_amdgcn_exp2f)
#define EXP2(x) __builtin_amdgcn_exp2f(x)
#else
#define EXP2(x) exp2f(x)
#endif

__device__ __forceinline__ u16 f2bf(float f) {
  union { float f; uint32_t u; } x; x.f = f;
  uint32_t r = (x.u + 0x7fffu + ((x.u >> 16) & 1u)) >> 16;
  return (u16)r;
}

__device__ __forceinline__ uint32_t cvtpk(float lo, float hi) {
  uint32_t r;
  asm volatile("v_cvt_pk_bf16_f32 %0, %1, %2" : "=v"(r) : "v"(lo), "v"(hi));
  return r;
}

__device__ __forceinline__ void gl_lds16(const void* g, void* l) {
  __builtin_amdgcn_global_load_lds(
      (const __attribute__((address_space(1))) uint32_t*)g,
      (__attribute__((address_space(3))) uint32_t*)l, 16, 0, 0);
}

// ---------------- weight-only cast fp32 -> bf16 (12 MB total) ----------------
__global__ __launch_bounds__(256) void cast_w(
    const float* __restrict__ s0, const float* __restrict__ s1,
    const float* __restrict__ s2, const float* __restrict__ s3,
    u16* __restrict__ d0, u16* __restrict__ d1,
    u16* __restrict__ d2, u16* __restrict__ d3) {
  int i = blockIdx.x * 256 + threadIdx.x;          // [0, 4*2^17)
  int sel = i >> 17, off = i & ((1 << 17) - 1);
  const float* s = sel == 0 ? s0 : sel == 1 ? s1 : sel == 2 ? s2 : s3;
  u16* d = sel == 0 ? d0 : sel == 1 ? d1 : sel == 2 ? d2 : d3;
  const float4* sp = (const float4*)s;
  float4 a = sp[off*2], b = sp[off*2+1];
  union { u16 h[8]; uint4 v; } o;
  o.h[0]=f2bf(a.x); o.h[1]=f2bf(a.y); o.h[2]=f2bf(a.z); o.h[3]=f2bf(a.w);
  o.h[4]=f2bf(b.x); o.h[5]=f2bf(b.y); o.h[6]=f2bf(b.z); o.h[7]=f2bf(b.w);
  *(uint4*)(d + (size_t)off*8) = o.v;
}

// ---------------- GEMM core v3: BK=64, single-buf, 2-barrier (R11 shape) ----
// Halves barrier/drain events vs BK=32 (R11: 64 drains -> 32). All tiles use
// the attn-K-verified both-sides swizzle slot^ (row&7): fp32 A rows = 16
// 16B-slots (XOR low 3 bits), bf16 A/B rows = 8 slots. All reads 2-way banks.
// gl_lds dest = base + tid*16 (linear, rule 21). A_FP32 converts via cvt_pk
// on the fragment read (no separate activation-cast pass).
template<int A_FP32, int OUT_BF16>
__device__ __forceinline__ void gemm_body(
    const void* __restrict__ Ap, const u16* __restrict__ W,
    const float* __restrict__ bias, void* __restrict__ Cout,
    int Ndim, int Kdim, float scale, int m0, int n0,
    char* AsB, char* BsB) {
  const int tid = threadIdx.x;
  const int lane = tid & 63, w = tid >> 6;
  const int wr = w >> 1, wc = w & 1;
  const int l15 = lane & 15, l4 = lane >> 4;

  f32x4 acc[4][4] = {};

  // bf16-tile staging indices (A when !A_FP32, and B always):
  // 128 rows x 64 k x 2B = 16KB, 4 issues; row = i*32 + (tid>>3), slot tid&7
  const int br = tid >> 3, bsl = tid & 7;
  // fp32 A staging: 128 rows x 64 k x 4B = 32KB, 8 issues;
  // row = i*16 + (tid>>4), slot tid&15 (16B slots), src slot ^= (row&7)
  const int ar = tid >> 4, asl = tid & 15;

  auto stage = [&](int k0) {
    if (A_FP32) {
      const float* Af = (const float*)Ap;
      #pragma unroll
      for (int i = 0; i < 8; ++i) {
        int row = i*16 + ar;
        int ss = asl ^ (row & 7);
        gl_lds16(Af + (size_t)(m0 + row)*Kdim + k0 + ss*4, AsB + i*4096 + tid*16);
      }
    } else {
      const u16* Ah = (const u16*)Ap;
      #pragma unroll
      for (int i = 0; i < 4; ++i) {
        int row = i*32 + br;
        int ss = bsl ^ (row & 7);
        gl_lds16(Ah + (size_t)(m0 + row)*Kdim + k0 + ss*8, AsB + i*4096 + tid*16);
      }
    }
    #pragma unroll
    for (int i = 0; i < 4; ++i) {
      int row = i*32 + br;
      int ss = bsl ^ (row & 7);
      gl_lds16(W + (size_t)(n0 + row)*Kdim + k0 + ss*8, BsB + i*4096 + tid*16);
    }
  };

  for (int k0 = 0; k0 < Kdim; k0 += 64) {
    stage(k0);
    __syncthreads();   // staging visible (vmcnt drained by syncthreads)

    bf16x8 af[2][4], bfr[2][4];
    #pragma unroll
    for (int m = 0; m < 4; ++m) {
      int r = wr*64 + m*16 + l15;
      if (A_FP32) {
        const char* rb = AsB + r*256;
        #pragma unroll
        for (int kk = 0; kk < 2; ++kk) {
          f32x4 fa = *(const f32x4*)(rb + (kk*8 + ((l4*2    ) ^ (r & 7)))*16);
          f32x4 fb = *(const f32x4*)(rb + (kk*8 + ((l4*2 + 1) ^ (r & 7)))*16);
          union { uint32_t u[4]; bf16x8 v; } cv;
          cv.u[0] = cvtpk(fa[0], fa[1]);
          cv.u[1] = cvtpk(fa[2], fa[3]);
          cv.u[2] = cvtpk(fb[0], fb[1]);
          cv.u[3] = cvtpk(fb[2], fb[3]);
          af[kk][m] = cv.v;
        }
      } else {
        const char* rb = AsB + r*128;
        #pragma unroll
        for (int kk = 0; kk < 2; ++kk)
          af[kk][m] = *(const bf16x8*)(rb + ((kk*4 + l4) ^ (r & 7))*16);
      }
    }
    #pragma unroll
    for (int n = 0; n < 4; ++n) {
      int rr = wc*64 + n*16 + l15;
      const char* rb = BsB + rr*128;
      #pragma unroll
      for (int kk = 0; kk < 2; ++kk)
        bfr[kk][n] = *(const bf16x8*)(rb + ((kk*4 + l4) ^ (rr & 7))*16);
    }
    #pragma unroll
    for (int kk = 0; kk < 2; ++kk)
      #pragma unroll
      for (int m = 0; m < 4; ++m)
        #pragma unroll
        for (int n = 0; n < 4; ++n)
          acc[m][n] = MFMA(af[kk][m], bfr[kk][n], acc[m][n], 0, 0, 0);
    __syncthreads();   // all reads done before next stage overwrites
  }

  const int ccol = wc*64 + l15;
  float bv[4];
  #pragma unroll
  for (int n = 0; n < 4; ++n) bv[n] = bias[n0 + ccol + n*16];
  #pragma unroll
  for (int m = 0; m < 4; ++m) {
    #pragma unroll
    for (int i = 0; i < 4; ++i) {
      size_t row = (size_t)(m0 + wr*64 + m*16 + l4*4 + i);
      #pragma unroll
      for (int n = 0; n < 4; ++n) {
        float v = (acc[m][n][i] + bv[n]) * scale;
        size_t idx = row * Ndim + (n0 + ccol + n*16);
        if (OUT_BF16) ((u16*)Cout)[idx] = f2bf(v);
        else          ((float*)Cout)[idx] = v;
      }
    }
  }
}

// merged Q/K/V projections, fp32-A staging, XCD chunk-swizzle (R11-verified).
// LDS 48KB -> 3 blocks/CU; 1536 blocks = exactly 2 rounds of 768.
__global__ __launch_bounds__(256, 2) void gemm_qkv(
    const float* __restrict__ qx, const float* __restrict__ kx, const float* __restrict__ vx,
    const u16* __restrict__ wqm, const u16* __restrict__ wkm, const u16* __restrict__ wvm,
    const float* __restrict__ qbv, const float* __restrict__ kbv, const float* __restrict__ vbv,
    u16* __restrict__ qo, u16* __restrict__ ko, u16* __restrict__ vo) {
  __shared__ alignas(16) char AsB[32768];   // fp32 A 128x64
  __shared__ alignas(16) char BsB[16384];   // bf16 B 128x64
  const int flat = blockIdx.x + blockIdx.y * 8 + blockIdx.z * 512;  // 0..1535
  const int j = flat & 7, s = flat >> 3;        // XCD, slot 0..191
  const int c = 6*j + (s >> 5), i = s & 31;     // chunk 0..47, block in chunk
  const int nx = i & 7;
  const int my = ((c & 15) << 2) + (i >> 3);    // 0..63
  const int z = c >> 4;
  const float* A = z == 0 ? qx : z == 1 ? kx : vx;
  const u16* W = z == 0 ? wqm : z == 1 ? wkm : wvm;
  const float* bias = z == 0 ? qbv : z == 1 ? kbv : vbv;
  u16* C = z == 0 ? qo : z == 1 ? ko : vo;
  const float scale = z == 0 ? 0.125f : 1.0f;
  gemm_body<1,1>(A, W, bias, C, EE, EE, scale, my * 128, nx * 128, AsB, BsB);
}

__global__ __launch_bounds__(256, 2) void gemm_out(
    const u16* __restrict__ A, const u16* __restrict__ W,
    const float* __restrict__ bias, float* __restrict__ Cout) {
  __shared__ alignas(16) char AsB[16384];
  __shared__ alignas(16) char BsB[16384];
  const int flat = blockIdx.x + blockIdx.y * 8;   // 0..511
  const int j = flat & 7, s = flat >> 3;          // XCD, slot 0..63
  const int nx = s & 7, yy = (j << 3) + (s >> 3); // XCD j -> m-panels 8j..8j+7
  gemm_body<0,0>(A, W, bias, Cout, EE, EE, 1.0f, yy * 128, nx * 128, AsB, BsB);
}

// ---------------- causal flash attention v9 (R10-verified, 75.8 us) --------
__global__ __launch_bounds__(256, 2) void attn9(
    const u16* __restrict__ Q, const u16* __restrict__ K,
    const u16* __restrict__ V, u16* __restrict__ ctx) {
  __shared__ alignas(16) u16 Ks[2][2][64*64];    // 32768 B
  __shared__ alignas(16) u16 VTs[2][2][64*64];   // 32768 B
  __shared__ alignas(16) u16 Ps[4][32*64];       // 16384 B

  const int tid = threadIdx.x, lane = tid & 63, w = tid >> 6;
  const int l15 = lane & 15, l4 = lane >> 4;

  const int f = blockIdx.x;               // 0..511
  const int j = f & 7, s = f >> 3;        // XCD, slot
  const int qlo = s & 7;
  const int panel = j * 8 + (s >> 3);     // 0..63
  const int h = panel & 15, b = panel >> 4;
  const size_t base = ((size_t)b * SS) * EE + h * DD;

  const int kr  = tid >> 3;
  const int ksl = tid & 7;
  const int rv  = tid >> 2;
  const int vc  = tid & 3;

  u16* KsE  = (u16*)Ks;
  u16* VTsE = (u16*)VTs;
  u16* PsE  = (u16*)Ps + w * 2048;

  auto stageK = [&](int t, int pb, int sub) {
    #pragma unroll
    for (int i = 0; i < 2; ++i) {
      int row = i*32 + kr;
      gl_lds16(K + base + (size_t)(t*64 + row)*EE + (ksl ^ (row & 7))*8,
               KsE + pb*8192 + sub*4096 + i*2048 + tid*8);
    }
  };
  auto vtWrite = [&](int pb, int sub, bf16x8 v0, bf16x8 v1) {
    #pragma unroll
    for (int jj = 0; jj < 16; ++jj) {
      u16 val = jj < 8 ? (u16)v0[jj] : (u16)v1[jj - 8];
      int d = vc*16 + jj;
      int sl = (rv >> 3) ^ (jj & 7) ^ (vc << 1);
      VTsE[pb*8192 + sub*4096 + d*64 + sl*8 + (rv & 7)] = val;
    }
  };

  #pragma unroll 1
  for (int pass = 0; pass < 2; ++pass) {
    const int qblk = pass == 0 ? (15 - qlo) : qlo;
    const int q0 = qblk * 128, wq = q0 + w * 32;
    const int npairs = qblk + 1;

    bf16x8 qf[2][2];
    #pragma unroll
    for (int G = 0; G < 2; ++G)
      #pragma unroll
      for (int kc = 0; kc < 2; ++kc)
        qf[G][kc] = *(const bf16x8*)(Q + base + (size_t)(wq + G*16 + l15)*EE + kc*32 + l4*8);

    f32x4 o[2][4] = {};
    float lsum[2] = {0.f, 0.f};

    auto computeTile = [&](int t, int pb, int sub) {
      if (wq + 31 < t*64) return;
      const bool g0act = (wq + 15 >= t*64);
      const u16* tileK = KsE + pb*8192 + sub*4096;
      const u16* tileV = VTsE + pb*8192 + sub*4096;

      f32x4 sc[2][4] = {};
      #pragma unroll
      for (int nt = 0; nt < 4; ++nt) {
        int row = nt*16 + l15;
        int sw = row & 7;
        const u16* kb = tileK + row*64;
        bf16x8 kf0 = *(const bf16x8*)(kb + ((l4    ) ^ sw)*8);
        bf16x8 kf1 = *(const bf16x8*)(kb + ((4 + l4) ^ sw)*8);
        sc[1][nt] = MFMA(kf0, qf[1][0], sc[1][nt], 0, 0, 0);
        sc[1][nt] = MFMA(kf1, qf[1][1], sc[1][nt], 0, 0, 0);
        if (g0act) {
          sc[0][nt] = MFMA(kf0, qf[0][0], sc[0][nt], 0, 0, 0);
          sc[0][nt] = MFMA(kf1, qf[0][1], sc[0][nt], 0, 0, 0);
        }
      }

      #pragma unroll
      for (int G = 0; G < 2; ++G) {
        if (G == 0 && !g0act) continue;
        const bool nomask = (t*64 + 63 <= wq + G*16);
        const int qg = wq + G*16 + l15;
        #pragma unroll
        for (int nt = 0; nt < 4; ++nt) {
          float p0 = EXP2(__builtin_fmaf(sc[G][nt][0], 1.44269504f, -17.3123405f));
          float p1 = EXP2(__builtin_fmaf(sc[G][nt][1], 1.44269504f, -17.3123405f));
          float p2 = EXP2(__builtin_fmaf(sc[G][nt][2], 1.44269504f, -17.3123405f));
          float p3 = EXP2(__builtin_fmaf(sc[G][nt][3], 1.44269504f, -17.3123405f));
          if (!nomask) {
            int kvs = t*64 + nt*16 + l4*4;
            if (kvs + 0 > qg) p0 = 0.f;
            if (kvs + 1 > qg) p1 = 0.f;
            if (kvs + 2 > qg) p2 = 0.f;
            if (kvs + 3 > qg) p3 = 0.f;
          }
          lsum[G] += (p0 + p1) + (p2 + p3);
          uint2 pk;
          pk.x = cvtpk(p0, p1);
          pk.y = cvtpk(p2, p3);
          *(uint2*)((char*)PsE + (G*16 + l15)*128
                        + (((nt*2 + (l4 >> 1)) ^ (l15 & 7)) * 16)
                        + (l4 & 1) * 8) = pk;
        }
      }

      #pragma unroll
      for (int cc = 0; cc < 2; ++cc) {
        bf16x8 pf1 = *(const bf16x8*)((char*)PsE + (16 + l15)*128
                                     + (((cc*4 + l4) ^ (l15 & 7)) * 16));
        bf16x8 pf0;
        if (g0act)
          pf0 = *(const bf16x8*)((char*)PsE + l15*128
                                     + (((cc*4 + l4) ^ (l15 & 7)) * 16));
        #pragma unroll
        for (int dm = 0; dm < 4; ++dm) {
          int sl = (cc*4 + l4) ^ (l15 & 7) ^ (dm << 1);
          bf16x8 vfv = *(const bf16x8*)(tileV + (dm*16 + l15)*64 + sl*8);
          o[1][dm] = MFMA(pf1, vfv, o[1][dm], 0, 0, 0);
          if (g0act) o[0][dm] = MFMA(pf0, vfv, o[0][dm], 0, 0, 0);
        }
      }
    };

    {
      const u16* va = V + base + (size_t)rv*EE + vc*16;
      const u16* vb = V + base + (size_t)(64 + rv)*EE + vc*16;
      bf16x8 a0 = *(const bf16x8*)va, a1 = *(const bf16x8*)(va + 8);
      bf16x8 b0 = *(const bf16x8*)vb, b1 = *(const bf16x8*)(vb + 8);
      stageK(0, 0, 0);
      stageK(1, 0, 1);
      vtWrite(0, 0, a0, a1);
      vtWrite(0, 1, b0, b1);
    }
    __syncthreads();

    for (int u = 0; u < npairs; ++u) {
      const int cur = u & 1;
      const bool havenext = (u + 1 < npairs);
      bf16x8 na0, na1, nb0, nb1;
      if (havenext) {
        const u16* va = V + base + (size_t)((2*u+2)*64 + rv)*EE + vc*16;
        const u16* vb = V + base + (size_t)((2*u+3)*64 + rv)*EE + vc*16;
        na0 = *(const bf16x8*)va; na1 = *(const bf16x8*)(va + 8);
        nb0 = *(const bf16x8*)vb; nb1 = *(const bf16x8*)(vb + 8);
        stageK(2*u+2, cur ^ 1, 0);
        stageK(2*u+3, cur ^ 1, 1);
      }

      computeTile(2*u, cur, 0);
      if (havenext) vtWrite(cur ^ 1, 0, na0, na1);
      computeTile(2*u + 1, cur, 1);
      if (havenext) vtWrite(cur ^ 1, 1, nb0, nb1);
      __syncthreads();
    }

    #pragma unroll
    for (int G = 0; G < 2; ++G) {
      float r = lsum[G];
      r += __shfl_xor(r, 16);
      r += __shfl_xor(r, 32);
      lsum[G] = 1.0f / r;
    }

    #pragma unroll
    for (int G = 0; G < 2; ++G)
      #pragma unroll
      for (int i = 0; i < 4; ++i) {
        float invv = __shfl(lsum[G], l4*4 + i);
        size_t roff = base + (size_t)(wq + G*16 + l4*4 + i) * EE;
        #pragma unroll
        for (int dm = 0; dm < 4; ++dm)
          ctx[roff + dm*16 + l15] = f2bf(o[G][dm][i] * invv);
      }
  }
}

// ---------------- launch ----------------
extern "C" void kernel_launch(void* const* d_in, const int* in_sizes, int n_in,
                              void* d_out, int out_size, void* d_ws, size_t ws_size,
                              hipStream_t stream) {
  const float* query = (const float*)d_in[0];
  const float* key   = (const float*)d_in[1];
  const float* value = (const float*)d_in[2];
  const float* q_w = (const float*)d_in[4];
  const float* q_b = (const float*)d_in[5];
  const float* k_w = (const float*)d_in[6];
  const float* k_b = (const float*)d_in[7];
  const float* v_w = (const float*)d_in[8];
  const float* v_b = (const float*)d_in[9];
  const float* o_w = (const float*)d_in[10];
  const float* o_b = (const float*)d_in[11];

  char* ws = (char*)d_ws;
  const size_t XB = (size_t)MM * EE * 2;   // 16 MB bf16 activation
  const size_t WB = (size_t)EE * EE * 2;   // 2 MB bf16 weight
  u16* wq = (u16*)(ws);
  u16* wk = (u16*)(ws + WB);
  u16* wv = (u16*)(ws + 2*WB);
  u16* wo = (u16*)(ws + 3*WB);
  u16* qp = (u16*)(ws + 4*WB);
  u16* kp = (u16*)(ws + 4*WB + XB);
  u16* vp = (u16*)(ws + 4*WB + 2*XB);
  u16* ctxb = (u16*)(ws + 4*WB + 3*XB);

  const int nw8 = EE * EE / 8;   // 2^17
  cast_w<<<4*nw8/256, 256, 0, stream>>>(q_w, k_w, v_w, o_w, wq, wk, wv, wo);

  gemm_qkv<<<dim3(8, 64, 3), 256, 0, stream>>>(
      query, key, value, wq, wk, wv, q_b, k_b, v_b, qp, kp, vp);

  attn9<<<512, 256, 0, stream>>>(qp, kp, vp, ctxb);

  gemm_out<<<dim3(EE/128, MM/128), 256, 0, stream>>>(ctxb, wo, o_b, (float*)d_out);
}

// Round 14
// 164.008 us; speedup vs baseline: 1.1002x; 1.0152x over previous
//
#include <hip/hip_runtime.h>
#include <stdint.h>

#define BB 4
#define SS 2048
#define EE 1024
#define HH 16
#define DD 64
#define MM (BB*SS)   // 8192

typedef unsigned short u16;
typedef __attribute__((ext_vector_type(8))) short bf16x8;
typedef __attribute__((ext_vector_type(4))) float f32x4;

#define MFMA __builtin_amdgcn_mfma_f32_16x16x32_bf16

#if __has_builtin(__builtin_amdgcn_exp2f)
#define EXP2(x) __builtin_amdgcn_exp2f(x)
#else
#define EXP2(x) exp2f(x)
#endif

__device__ __forceinline__ u16 f2bf(float f) {
  union { float f; uint32_t u; } x; x.f = f;
  uint32_t r = (x.u + 0x7fffu + ((x.u >> 16) & 1u)) >> 16;
  return (u16)r;
}

__device__ __forceinline__ uint32_t cvtpk(float lo, float hi) {
  uint32_t r;
  asm volatile("v_cvt_pk_bf16_f32 %0, %1, %2" : "=v"(r) : "v"(lo), "v"(hi));
  return r;
}

__device__ __forceinline__ void gl_lds16(const void* g, void* l) {
  __builtin_amdgcn_global_load_lds(
      (const __attribute__((address_space(1))) uint32_t*)g,
      (__attribute__((address_space(3))) uint32_t*)l, 16, 0, 0);
}

// ---------------- weight-only cast fp32 -> bf16 (12 MB total) ----------------
__global__ __launch_bounds__(256) void cast_w(
    const float* __restrict__ s0, const float* __restrict__ s1,
    const float* __restrict__ s2, const float* __restrict__ s3,
    u16* __restrict__ d0, u16* __restrict__ d1,
    u16* __restrict__ d2, u16* __restrict__ d3) {
  int i = blockIdx.x * 256 + threadIdx.x;          // [0, 4*2^17)
  int sel = i >> 17, off = i & ((1 << 17) - 1);
  const float* s = sel == 0 ? s0 : sel == 1 ? s1 : sel == 2 ? s2 : s3;
  u16* d = sel == 0 ? d0 : sel == 1 ? d1 : sel == 2 ? d2 : d3;
  const float4* sp = (const float4*)s;
  float4 a = sp[off*2], b = sp[off*2+1];
  union { u16 h[8]; uint4 v; } o;
  o.h[0]=f2bf(a.x); o.h[1]=f2bf(a.y); o.h[2]=f2bf(a.z); o.h[3]=f2bf(a.w);
  o.h[4]=f2bf(b.x); o.h[5]=f2bf(b.y); o.h[6]=f2bf(b.z); o.h[7]=f2bf(b.w);
  *(uint4*)(d + (size_t)off*8) = o.v;
}

// ---------------- GEMM core v3: BK=64, single-buf, 2-barrier (R13, verified) -
template<int A_FP32, int OUT_BF16>
__device__ __forceinline__ void gemm_body(
    const void* __restrict__ Ap, const u16* __restrict__ W,
    const float* __restrict__ bias, void* __restrict__ Cout,
    int Ndim, int Kdim, float scale, int m0, int n0,
    char* AsB, char* BsB) {
  const int tid = threadIdx.x;
  const int lane = tid & 63, w = tid >> 6;
  const int wr = w >> 1, wc = w & 1;
  const int l15 = lane & 15, l4 = lane >> 4;

  f32x4 acc[4][4] = {};

  const int br = tid >> 3, bsl = tid & 7;
  const int ar = tid >> 4, asl = tid & 15;

  auto stage = [&](int k0) {
    if (A_FP32) {
      const float* Af = (const float*)Ap;
      #pragma unroll
      for (int i = 0; i < 8; ++i) {
        int row = i*16 + ar;
        int ss = asl ^ (row & 7);
        gl_lds16(Af + (size_t)(m0 + row)*Kdim + k0 + ss*4, AsB + i*4096 + tid*16);
      }
    } else {
      const u16* Ah = (const u16*)Ap;
      #pragma unroll
      for (int i = 0; i < 4; ++i) {
        int row = i*32 + br;
        int ss = bsl ^ (row & 7);
        gl_lds16(Ah + (size_t)(m0 + row)*Kdim + k0 + ss*8, AsB + i*4096 + tid*16);
      }
    }
    #pragma unroll
    for (int i = 0; i < 4; ++i) {
      int row = i*32 + br;
      int ss = bsl ^ (row & 7);
      gl_lds16(W + (size_t)(n0 + row)*Kdim + k0 + ss*8, BsB + i*4096 + tid*16);
    }
  };

  for (int k0 = 0; k0 < Kdim; k0 += 64) {
    stage(k0);
    __syncthreads();

    bf16x8 af[2][4], bfr[2][4];
    #pragma unroll
    for (int m = 0; m < 4; ++m) {
      int r = wr*64 + m*16 + l15;
      if (A_FP32) {
        const char* rb = AsB + r*256;
        #pragma unroll
        for (int kk = 0; kk < 2; ++kk) {
          f32x4 fa = *(const f32x4*)(rb + (kk*8 + ((l4*2    ) ^ (r & 7)))*16);
          f32x4 fb = *(const f32x4*)(rb + (kk*8 + ((l4*2 + 1) ^ (r & 7)))*16);
          union { uint32_t u[4]; bf16x8 v; } cv;
          cv.u[0] = cvtpk(fa[0], fa[1]);
          cv.u[1] = cvtpk(fa[2], fa[3]);
          cv.u[2] = cvtpk(fb[0], fb[1]);
          cv.u[3] = cvtpk(fb[2], fb[3]);
          af[kk][m] = cv.v;
        }
      } else {
        const char* rb = AsB + r*128;
        #pragma unroll
        for (int kk = 0; kk < 2; ++kk)
          af[kk][m] = *(const bf16x8*)(rb + ((kk*4 + l4) ^ (r & 7))*16);
      }
    }
    #pragma unroll
    for (int n = 0; n < 4; ++n) {
      int rr = wc*64 + n*16 + l15;
      const char* rb = BsB + rr*128;
      #pragma unroll
      for (int kk = 0; kk < 2; ++kk)
        bfr[kk][n] = *(const bf16x8*)(rb + ((kk*4 + l4) ^ (rr & 7))*16);
    }
    #pragma unroll
    for (int kk = 0; kk < 2; ++kk)
      #pragma unroll
      for (int m = 0; m < 4; ++m)
        #pragma unroll
        for (int n = 0; n < 4; ++n)
          acc[m][n] = MFMA(af[kk][m], bfr[kk][n], acc[m][n], 0, 0, 0);
    __syncthreads();
  }

  const int ccol = wc*64 + l15;
  float bv[4];
  #pragma unroll
  for (int n = 0; n < 4; ++n) bv[n] = bias[n0 + ccol + n*16];
  #pragma unroll
  for (int m = 0; m < 4; ++m) {
    #pragma unroll
    for (int i = 0; i < 4; ++i) {
      size_t row = (size_t)(m0 + wr*64 + m*16 + l4*4 + i);
      #pragma unroll
      for (int n = 0; n < 4; ++n) {
        float v = (acc[m][n][i] + bv[n]) * scale;
        size_t idx = row * Ndim + (n0 + ccol + n*16);
        if (OUT_BF16) ((u16*)Cout)[idx] = f2bf(v);
        else          ((float*)Cout)[idx] = v;
      }
    }
  }
}

// merged Q/K/V projections, fp32-A staging, XCD chunk-swizzle (R13-verified).
__global__ __launch_bounds__(256, 2) void gemm_qkv(
    const float* __restrict__ qx, const float* __restrict__ kx, const float* __restrict__ vx,
    const u16* __restrict__ wqm, const u16* __restrict__ wkm, const u16* __restrict__ wvm,
    const float* __restrict__ qbv, const float* __restrict__ kbv, const float* __restrict__ vbv,
    u16* __restrict__ qo, u16* __restrict__ ko, u16* __restrict__ vo) {
  __shared__ alignas(16) char AsB[32768];   // fp32 A 128x64
  __shared__ alignas(16) char BsB[16384];   // bf16 B 128x64
  const int flat = blockIdx.x + blockIdx.y * 8 + blockIdx.z * 512;  // 0..1535
  const int j = flat & 7, s = flat >> 3;        // XCD, slot 0..191
  const int c = 6*j + (s >> 5), i = s & 31;     // chunk 0..47, block in chunk
  const int nx = i & 7;
  const int my = ((c & 15) << 2) + (i >> 3);    // 0..63
  const int z = c >> 4;
  const float* A = z == 0 ? qx : z == 1 ? kx : vx;
  const u16* W = z == 0 ? wqm : z == 1 ? wkm : wvm;
  const float* bias = z == 0 ? qbv : z == 1 ? kbv : vbv;
  u16* C = z == 0 ? qo : z == 1 ? ko : vo;
  const float scale = z == 0 ? 0.125f : 1.0f;
  gemm_body<1,1>(A, W, bias, C, EE, EE, scale, my * 128, nx * 128, AsB, BsB);
}

__global__ __launch_bounds__(256, 4) void gemm_out(
    const u16* __restrict__ A, const u16* __restrict__ W,
    const float* __restrict__ bias, float* __restrict__ Cout) {
  __shared__ alignas(16) char AsB[16384];
  __shared__ alignas(16) char BsB[16384];
  const int flat = blockIdx.x + blockIdx.y * 8;   // 0..511
  const int j = flat & 7, s = flat >> 3;          // XCD, slot 0..63
  const int nx = s & 7, yy = (j << 3) + (s >> 3); // XCD j -> m-panels 8j..8j+7
  gemm_body<0,0>(A, W, bias, Cout, EE, EE, 1.0f, yy * 128, nx * 128, AsB, BsB);
}

// ---------------- causal flash attention v10 (R10 structure + setprio T5) --
__global__ __launch_bounds__(256, 2) void attn10(
    const u16* __restrict__ Q, const u16* __restrict__ K,
    const u16* __restrict__ V, u16* __restrict__ ctx) {
  __shared__ alignas(16) u16 Ks[2][2][64*64];    // 32768 B
  __shared__ alignas(16) u16 VTs[2][2][64*64];   // 32768 B
  __shared__ alignas(16) u16 Ps[4][32*64];       // 16384 B

  const int tid = threadIdx.x, lane = tid & 63, w = tid >> 6;
  const int l15 = lane & 15, l4 = lane >> 4;

  const int f = blockIdx.x;               // 0..511
  const int j = f & 7, s = f >> 3;        // XCD, slot
  const int qlo = s & 7;
  const int panel = j * 8 + (s >> 3);     // 0..63
  const int h = panel & 15, b = panel >> 4;
  const size_t base = ((size_t)b * SS) * EE + h * DD;

  const int kr  = tid >> 3;
  const int ksl = tid & 7;
  const int rv  = tid >> 2;
  const int vc  = tid & 3;

  u16* KsE  = (u16*)Ks;
  u16* VTsE = (u16*)VTs;
  u16* PsE  = (u16*)Ps + w * 2048;

  auto stageK = [&](int t, int pb, int sub) {
    #pragma unroll
    for (int i = 0; i < 2; ++i) {
      int row = i*32 + kr;
      gl_lds16(K + base + (size_t)(t*64 + row)*EE + (ksl ^ (row & 7))*8,
               KsE + pb*8192 + sub*4096 + i*2048 + tid*8);
    }
  };
  auto vtWrite = [&](int pb, int sub, bf16x8 v0, bf16x8 v1) {
    #pragma unroll
    for (int jj = 0; jj < 16; ++jj) {
      u16 val = jj < 8 ? (u16)v0[jj] : (u16)v1[jj - 8];
      int d = vc*16 + jj;
      int sl = (rv >> 3) ^ (jj & 7) ^ (vc << 1);
      VTsE[pb*8192 + sub*4096 + d*64 + sl*8 + (rv & 7)] = val;
    }
  };

  #pragma unroll 1
  for (int pass = 0; pass < 2; ++pass) {
    const int qblk = pass == 0 ? (15 - qlo) : qlo;
    const int q0 = qblk * 128, wq = q0 + w * 32;
    const int npairs = qblk + 1;

    bf16x8 qf[2][2];
    #pragma unroll
    for (int G = 0; G < 2; ++G)
      #pragma unroll
      for (int kc = 0; kc < 2; ++kc)
        qf[G][kc] = *(const bf16x8*)(Q + base + (size_t)(wq + G*16 + l15)*EE + kc*32 + l4*8);

    f32x4 o[2][4] = {};
    float lsum[2] = {0.f, 0.f};

    auto computeTile = [&](int t, int pb, int sub) {
      if (wq + 31 < t*64) return;
      const bool g0act = (wq + 15 >= t*64);
      const u16* tileK = KsE + pb*8192 + sub*4096;
      const u16* tileV = VTsE + pb*8192 + sub*4096;

      f32x4 sc[2][4] = {};
      __builtin_amdgcn_s_setprio(1);          // T5: favor MFMA wave vs other block
      #pragma unroll
      for (int nt = 0; nt < 4; ++nt) {
        int row = nt*16 + l15;
        int sw = row & 7;
        const u16* kb = tileK + row*64;
        bf16x8 kf0 = *(const bf16x8*)(kb + ((l4    ) ^ sw)*8);
        bf16x8 kf1 = *(const bf16x8*)(kb + ((4 + l4) ^ sw)*8);
        sc[1][nt] = MFMA(kf0, qf[1][0], sc[1][nt], 0, 0, 0);
        sc[1][nt] = MFMA(kf1, qf[1][1], sc[1][nt], 0, 0, 0);
        if (g0act) {
          sc[0][nt] = MFMA(kf0, qf[0][0], sc[0][nt], 0, 0, 0);
          sc[0][nt] = MFMA(kf1, qf[0][1], sc[0][nt], 0, 0, 0);
        }
      }
      __builtin_amdgcn_s_setprio(0);

      #pragma unroll
      for (int G = 0; G < 2; ++G) {
        if (G == 0 && !g0act) continue;
        const bool nomask = (t*64 + 63 <= wq + G*16);
        const int qg = wq + G*16 + l15;
        #pragma unroll
        for (int nt = 0; nt < 4; ++nt) {
          float p0 = EXP2(__builtin_fmaf(sc[G][nt][0], 1.44269504f, -17.3123405f));
          float p1 = EXP2(__builtin_fmaf(sc[G][nt][1], 1.44269504f, -17.3123405f));
          float p2 = EXP2(__builtin_fmaf(sc[G][nt][2], 1.44269504f, -17.3123405f));
          float p3 = EXP2(__builtin_fmaf(sc[G][nt][3], 1.44269504f, -17.3123405f));
          if (!nomask) {
            int kvs = t*64 + nt*16 + l4*4;
            if (kvs + 0 > qg) p0 = 0.f;
            if (kvs + 1 > qg) p1 = 0.f;
            if (kvs + 2 > qg) p2 = 0.f;
            if (kvs + 3 > qg) p3 = 0.f;
          }
          lsum[G] += (p0 + p1) + (p2 + p3);
          uint2 pk;
          pk.x = cvtpk(p0, p1);
          pk.y = cvtpk(p2, p3);
          *(uint2*)((char*)PsE + (G*16 + l15)*128
                        + (((nt*2 + (l4 >> 1)) ^ (l15 & 7)) * 16)
                        + (l4 & 1) * 8) = pk;
        }
      }

      __builtin_amdgcn_s_setprio(1);          // T5: PV MFMA cluster
      #pragma unroll
      for (int cc = 0; cc < 2; ++cc) {
        bf16x8 pf1 = *(const bf16x8*)((char*)PsE + (16 + l15)*128
                                     + (((cc*4 + l4) ^ (l15 & 7)) * 16));
        bf16x8 pf0;
        if (g0act)
          pf0 = *(const bf16x8*)((char*)PsE + l15*128
                                     + (((cc*4 + l4) ^ (l15 & 7)) * 16));
        #pragma unroll
        for (int dm = 0; dm < 4; ++dm) {
          int sl = (cc*4 + l4) ^ (l15 & 7) ^ (dm << 1);
          bf16x8 vfv = *(const bf16x8*)(tileV + (dm*16 + l15)*64 + sl*8);
          o[1][dm] = MFMA(pf1, vfv, o[1][dm], 0, 0, 0);
          if (g0act) o[0][dm] = MFMA(pf0, vfv, o[0][dm], 0, 0, 0);
        }
      }
      __builtin_amdgcn_s_setprio(0);
    };

    {
      const u16* va = V + base + (size_t)rv*EE + vc*16;
      const u16* vb = V + base + (size_t)(64 + rv)*EE + vc*16;
      bf16x8 a0 = *(const bf16x8*)va, a1 = *(const bf16x8*)(va + 8);
      bf16x8 b0 = *(const bf16x8*)vb, b1 = *(const bf16x8*)(vb + 8);
      stageK(0, 0, 0);
      stageK(1, 0, 1);
      vtWrite(0, 0, a0, a1);
      vtWrite(0, 1, b0, b1);
    }
    __syncthreads();

    for (int u = 0; u < npairs; ++u) {
      const int cur = u & 1;
      const bool havenext = (u + 1 < npairs);
      bf16x8 na0, na1, nb0, nb1;
      if (havenext) {
        const u16* va = V + base + (size_t)((2*u+2)*64 + rv)*EE + vc*16;
        const u16* vb = V + base + (size_t)((2*u+3)*64 + rv)*EE + vc*16;
        na0 = *(const bf16x8*)va; na1 = *(const bf16x8*)(va + 8);
        nb0 = *(const bf16x8*)vb; nb1 = *(const bf16x8*)(vb + 8);
        stageK(2*u+2, cur ^ 1, 0);
        stageK(2*u+3, cur ^ 1, 1);
      }

      computeTile(2*u, cur, 0);
      if (havenext) vtWrite(cur ^ 1, 0, na0, na1);
      computeTile(2*u + 1, cur, 1);
      if (havenext) vtWrite(cur ^ 1, 1, nb0, nb1);
      __syncthreads();
    }

    #pragma unroll
    for (int G = 0; G < 2; ++G) {
      float r = lsum[G];
      r += __shfl_xor(r, 16);
      r += __shfl_xor(r, 32);
      lsum[G] = 1.0f / r;
    }

    #pragma unroll
    for (int G = 0; G < 2; ++G)
      #pragma unroll
      for (int i = 0; i < 4; ++i) {
        float invv = __shfl(lsum[G], l4*4 + i);
        size_t roff = base + (size_t)(wq + G*16 + l4*4 + i) * EE;
        #pragma unroll
        for (int dm = 0; dm < 4; ++dm)
          ctx[roff + dm*16 + l15] = f2bf(o[G][dm][i] * invv);
      }
  }
}

// ---------------- launch ----------------
extern "C" void kernel_launch(void* const* d_in, const int* in_sizes, int n_in,
                              void* d_out, int out_size, void* d_ws, size_t ws_size,
                              hipStream_t stream) {
  const float* query = (const float*)d_in[0];
  const float* key   = (const float*)d_in[1];
  const float* value = (const float*)d_in[2];
  const float* q_w = (const float*)d_in[4];
  const float* q_b = (const float*)d_in[5];
  const float* k_w = (const float*)d_in[6];
  const float* k_b = (const float*)d_in[7];
  const float* v_w = (const float*)d_in[8];
  const float* v_b = (const float*)d_in[9];
  const float* o_w = (const float*)d_in[10];
  const float* o_b = (const float*)d_in[11];

  char* ws = (char*)d_ws;
  const size_t XB = (size_t)MM * EE * 2;   // 16 MB bf16 activation
  const size_t WB = (size_t)EE * EE * 2;   // 2 MB bf16 weight
  u16* wq = (u16*)(ws);
  u16* wk = (u16*)(ws + WB);
  u16* wv = (u16*)(ws + 2*WB);
  u16* wo = (u16*)(ws + 3*WB);
  u16* qp = (u16*)(ws + 4*WB);
  u16* kp = (u16*)(ws + 4*WB + XB);
  u16* vp = (u16*)(ws + 4*WB + 2*XB);
  u16* ctxb = (u16*)(ws + 4*WB + 3*XB);

  const int nw8 = EE * EE / 8;   // 2^17
  cast_w<<<4*nw8/256, 256, 0, stream>>>(q_w, k_w, v_w, o_w, wq, wk, wv, wo);

  gemm_qkv<<<dim3(8, 64, 3), 256, 0, stream>>>(
      query, key, value, wq, wk, wv, q_b, k_b, v_b, qp, kp, vp);

  attn10<<<512, 256, 0, stream>>>(qp, kp, vp, ctxb);

  gemm_out<<<dim3(EE/128, MM/128), 256, 0, stream>>>(ctxb, wo, o_b, (float*)d_out);
}